// Round 9
// baseline (521.852 us; speedup 1.0000x reference)
//
#include <hip/hip_runtime.h>
#include <stdint.h>

typedef __attribute__((ext_vector_type(8))) short short8;
typedef __attribute__((ext_vector_type(4))) float f32x4;

#define T_STEPS 256
#define BATCH   128

// LDS-visibility barrier that does NOT drain vmcnt (global ops stay in flight)
#define LDS_BARRIER() asm volatile("s_waitcnt lgkmcnt(0)\n\ts_barrier" ::: "memory")

static __device__ inline unsigned short f2bf(float f) {   // RNE fp32->bf16 (W2 hi/lo path)
    unsigned int u = __float_as_uint(f);
    unsigned int r = u + 0x7FFFu + ((u >> 16) & 1u);
    return (unsigned short)(r >> 16);
}
static __device__ inline unsigned pack_hi16(unsigned a, unsigned b) {
    return (a >> 16) | (b & 0xFFFF0000u);
}

// ---- k_prep: 0..255 W2 hi/lo split; 256..257 W1 3-split rows (scaled 1/thr1);
//      258..769 X B-fragments; 770..1027 poison spike buffer with 0xAA
__global__ __launch_bounds__(256) void k_prep(
    const float* __restrict__ W2, const float* __restrict__ W1,
    const float* __restrict__ b1, const float* __restrict__ thr1,
    const float* __restrict__ imin_p, const float* __restrict__ imax_p,
    const float* __restrict__ batch,
    unsigned short* __restrict__ W2hi, unsigned short* __restrict__ W2lo,
    unsigned short* __restrict__ W1rows, float* __restrict__ b1s,
    unsigned short* __restrict__ Xf, unsigned* __restrict__ spkglob)
{
    int blk = blockIdx.x, tid = threadIdx.x;
    if (blk < 256) {
        int gid = blk * 256 + tid;
        f32x4 wv = *(const f32x4*)(W2 + (size_t)gid * 4);
        unsigned short hi[4], lo[4];
#pragma unroll
        for (int e = 0; e < 4; ++e) {
            float wf = wv[e];
            unsigned short h = f2bf(wf);
            float hf = __uint_as_float(((unsigned int)h) << 16);
            hi[e] = h;
            lo[e] = f2bf(wf - hf);
        }
        uint2 ph, pl;
        ph.x = (unsigned)hi[0] | ((unsigned)hi[1] << 16);
        ph.y = (unsigned)hi[2] | ((unsigned)hi[3] << 16);
        pl.x = (unsigned)lo[0] | ((unsigned)lo[1] << 16);
        pl.y = (unsigned)lo[2] | ((unsigned)lo[3] << 16);
        *(uint2*)(W2hi + (size_t)gid * 4) = ph;
        *(uint2*)(W2lo + (size_t)gid * 4) = pl;
    } else if (blk < 258) {
        int h = (blk - 256) * 256 + tid;
        float wsc = 1.0f / thr1[h];
        unsigned short row[64];
#pragma unroll
        for (int k = 0; k < 16; ++k) {
            float wv = W1[h * 16 + k] * wsc;
            unsigned a = __float_as_uint(wv) & 0xFFFF0000u;
            float r1 = wv - __uint_as_float(a);
            unsigned m = __float_as_uint(r1) & 0xFFFF0000u;
            float r2 = r1 - __uint_as_float(m);
            unsigned l = __float_as_uint(r2) & 0xFFFF0000u;
            row[k]      = (unsigned short)(a >> 16);
            row[16 + k] = (unsigned short)(m >> 16);
            row[32 + k] = (unsigned short)(l >> 16);
            row[48 + k] = 0;
        }
        b1s[h] = b1[h] * wsc;
        uint4* dst = (uint4*)(W1rows + (size_t)h * 64);
#pragma unroll
        for (int i = 0; i < 8; ++i) dst[i] = ((uint4*)row)[i];
    } else if (blk < 770) {
        int gid   = (blk - 258) * 256 + tid;
        int lane  = gid & 63;
        int btile = (gid >> 6) & 7;
        int t     = gid >> 9;
        int q     = lane >> 4, m15 = lane & 15;
        int b     = btile * 16 + m15;
        float imin = imin_p[0];
        float isc  = 1.0f / (imax_p[0] - imin);
        const float* xp = batch + ((size_t)b * T_STEPS + t) * 16 + (q & 1) * 8;
        unsigned uh[8], um[8], ul[8];
#pragma unroll
        for (int j = 0; j < 8; ++j) {
            float xv = (xp[j] - imin) * isc;
            unsigned a = __float_as_uint(xv) & 0xFFFF0000u;
            float r1 = xv - __uint_as_float(a);
            unsigned m = __float_as_uint(r1) & 0xFFFF0000u;
            float r2 = r1 - __uint_as_float(m);
            unsigned l = __float_as_uint(r2) & 0xFFFF0000u;
            uh[j] = a; um[j] = m; ul[j] = l;
        }
        uint4 B1, B2, XL;
        B1.x = pack_hi16(uh[0], uh[1]); B1.y = pack_hi16(uh[2], uh[3]);
        B1.z = pack_hi16(uh[4], uh[5]); B1.w = pack_hi16(uh[6], uh[7]);
        B2.x = pack_hi16(um[0], um[1]); B2.y = pack_hi16(um[2], um[3]);
        B2.z = pack_hi16(um[4], um[5]); B2.w = pack_hi16(um[6], um[7]);
        XL.x = pack_hi16(ul[0], ul[1]); XL.y = pack_hi16(ul[2], ul[3]);
        XL.z = pack_hi16(ul[4], ul[5]); XL.w = pack_hi16(ul[6], ul[7]);
        uint4 B3 = (q < 2) ? XL : B1;   // [xl|xh]
        unsigned short* dst = Xf + (((size_t)t * 8 + btile) * 3) * 512 + lane * 8;
        *(uint4*)(dst +    0) = B1;
        *(uint4*)(dst +  512) = B2;
        *(uint4*)(dst + 1024) = B3;
    } else {
        // poison 258 t-slots x 8 btiles x 512 dwords = 1,056,768 dwords
        int pb = blk - 770;                 // 0..257
        unsigned* dst = spkglob + ((size_t)pb * 256 + tid) * 16;
        uint4 P = { 0xAAAAAAAAu, 0xAAAAAAAAu, 0xAAAAAAAAu, 0xAAAAAAAAu };
#pragma unroll
        for (int i = 0; i < 4; ++i) *(uint4*)(dst + i * 4) = P;
    }
}

// ---- main: 256 blocks x 16 waves. Block (btile,slice): wave0 produces spikes for its
//      16 h (2 steps ahead, volatile store, canary-tagged); all waves consume full 512-h
//      spike set via volatile loads (1 step ahead) -> GEMM2 -> reduce -> LIF2.
__global__ __launch_bounds__(1024, 4) void k_main(
    const unsigned short* __restrict__ Xf,
    const unsigned short* __restrict__ W2hi, const unsigned short* __restrict__ W2lo,
    const unsigned short* __restrict__ W1rows, const float* __restrict__ b1s,
    const float* __restrict__ beta1, const float* __restrict__ b2,
    const float* __restrict__ beta2, const float* __restrict__ thr2,
    unsigned* __restrict__ spkglob, unsigned short* __restrict__ spkbits)
{
    __shared__ float Cbuf[2][4096];       // [buf][r 4][wp 16][lane^swz 64]

    int tid  = threadIdx.x;
    int lane = tid & 63;
    int w    = tid >> 6;
    int q    = lane >> 4, m15 = lane & 15;
    int btile = blockIdx.x & 7;
    int slice = blockIdx.x >> 3;
    int rr = w & 3, qi = w >> 2;

    // ---- consumer: W2 B-frags for K-window [w*32, w*32+32)
    int jg = slice * 16 + m15;
    short8 bhi = *(const short8*)(W2hi + (size_t)jg * 512 + w * 32 + q * 8);
    short8 blo = *(const short8*)(W2lo + (size_t)jg * 512 + w * 32 + q * 8);

    float beta2r = fminf(fmaxf(beta2[jg], 0.0f), 1.0f);
    float thr2r  = thr2[jg];
    float nthr2  = -thr2r;
    float b2r    = b2[jg];
    float m2 = 0.0f, spk2f = 0.0f;

    int sidx = w * 64 + (lane ^ (qi * 16));
    int ridx = rr * 1024 + q * 256 + ((qi ^ q) * 16 + m15);
    unsigned short* spkp = spkbits + ((size_t)btile * 16 + (qi * 4 + rr)) * 32 + slice;

    // ---- producer state (wave 0 only uses it; init harmless for others)
    const unsigned short* rp = W1rows + (size_t)(slice * 16 + m15) * 64;
    short8 A1p = *(const short8*)(rp + q * 8);
    short8 A2p = *(const short8*)(rp + q * 8 + (q >> 1) * 16);
    int h0p = slice * 16 + q * 4;
    f32x4 b14p = *(const f32x4*)(b1s + h0p);
    f32x4 bet1p;
    {
        f32x4 bb = *(const f32x4*)(beta1 + h0p);
#pragma unroll
        for (int r = 0; r < 4; ++r) bet1p[r] = fminf(fmaxf(bb[r], 0.0f), 1.0f);
    }
    float m1p[4] = { 0.f, 0.f, 0.f, 0.f }, sp1p[4] = { 0.f, 0.f, 0.f, 0.f };

    const unsigned short* xbase = Xf + ((size_t)btile * 3) * 512 + lane * 8;
    unsigned* pstore = spkglob + (size_t)btile * 512 + slice * 16 + lane;   // + t*4096 (lane<16)
    const unsigned* cbase = spkglob + (size_t)btile * 512 + w * 32 + q * 8; // + t*4096

    uint4 x0[3];

    auto ldx = [&](int t) __attribute__((always_inline)) {
        int tn = (t < T_STEPS) ? t : T_STEPS - 1;
        const unsigned short* xp = xbase + (size_t)tn * 12288;
#pragma unroll
        for (int f = 0; f < 3; ++f) x0[f] = *(const uint4*)(xp + f * 512);
    };
    auto produce = [&](int t) __attribute__((always_inline)) {
        union { uint4 u; short8 s; } B0, B1, B2;
        B0.u = x0[0]; B1.u = x0[1]; B2.u = x0[2];
        f32x4 D = b14p;
        D = __builtin_amdgcn_mfma_f32_16x16x32_bf16(A1p, B0.s, D, 0, 0, 0);
        D = __builtin_amdgcn_mfma_f32_16x16x32_bf16(A1p, B1.s, D, 0, 0, 0);
        D = __builtin_amdgcn_mfma_f32_16x16x32_bf16(A2p, B2.s, D, 0, 0, 0);
        unsigned long long mk[4];
#pragma unroll
        for (int r = 0; r < 4; ++r) {
            float mv = fmaf(bet1p[r], m1p[r], D[r]);
            mv -= sp1p[r];
            bool sp = mv > 1.0f;
            m1p[r] = mv;
            sp1p[r] = sp ? 1.0f : 0.0f;
            mk[r] = __ballot(sp);
        }
        if (lane < 16) {
            int rs = lane & 3, qs = lane >> 2;
            unsigned long long mv_ = mk[0];
            mv_ = (rs == 1) ? mk[1] : mv_;
            mv_ = (rs == 2) ? mk[2] : mv_;
            mv_ = (rs == 3) ? mk[3] : mv_;
            unsigned dw  = (qs & 2) ? (unsigned)(mv_ >> 32) : (unsigned)mv_;
            unsigned v16 = (qs & 1) ? (dw >> 16) : (dw & 0xFFFFu);
            *(volatile unsigned*)(pstore + (size_t)t * 4096) = v16 | 0x55550000u;
        }
    };
    auto cload = [&](int t, uint4& a, uint4& b) __attribute__((always_inline)) {
        volatile const unsigned* p = cbase + (size_t)t * 4096;
        a.x = p[0]; a.y = p[1]; a.z = p[2]; a.w = p[3];
        b.x = p[4]; b.y = p[5]; b.z = p[6]; b.w = p[7];
    };
    auto consume = [&](int t, uint4 a, uint4 b, float* cb) __attribute__((always_inline)) {
        // canary-validate (unwritten dwords are 0xAAAAAAAA)
        while (true) {
            unsigned acc = a.x & a.y & a.z & a.w & b.x & b.y & b.z & b.w;
            if (__all((acc >> 16) == 0x5555u)) break;
            cload(t, a, b);
        }
        // expand bit m15 of 8 h-dwords -> bf16 A-frag
        union { unsigned u[4]; short8 s; } af;
        af.u[0] = (((a.x >> m15) & 1) ? 0x3F80u : 0u) | (((a.y >> m15) & 1) ? 0x3F800000u : 0u);
        af.u[1] = (((a.z >> m15) & 1) ? 0x3F80u : 0u) | (((a.w >> m15) & 1) ? 0x3F800000u : 0u);
        af.u[2] = (((b.x >> m15) & 1) ? 0x3F80u : 0u) | (((b.y >> m15) & 1) ? 0x3F800000u : 0u);
        af.u[3] = (((b.z >> m15) & 1) ? 0x3F80u : 0u) | (((b.w >> m15) & 1) ? 0x3F800000u : 0u);
        f32x4 C2 = { 0.f, 0.f, 0.f, 0.f };
        C2 = __builtin_amdgcn_mfma_f32_16x16x32_bf16(af.s, bhi, C2, 0, 0, 0);
        C2 = __builtin_amdgcn_mfma_f32_16x16x32_bf16(af.s, blo, C2, 0, 0, 0);
        cb[sidx]        = C2[0];
        cb[sidx + 1024] = C2[1];
        cb[sidx + 2048] = C2[2];
        cb[sidx + 3072] = C2[3];
    };
    auto rtail = [&](const float* cb) __attribute__((always_inline)) {
        float s0 = cb[ridx], s1 = cb[ridx + 64], s2 = cb[ridx + 128], s3 = cb[ridx + 192];
        float s = (s0 + s1) + (s2 + s3);
        s += __shfl_xor(s, 16, 64);
        s += __shfl_xor(s, 32, 64);
        m2 = fmaf(beta2r, m2, b2r + s);
        m2 = fmaf(spk2f, nthr2, m2);
        bool sp2 = m2 > thr2r;
        spk2f = sp2 ? 1.0f : 0.0f;
        unsigned long long mask = __ballot(sp2);
        if (lane == 0) *spkp = (unsigned short)(mask & 0xFFFFu);
        spkp += BATCH * 32;
    };

    // ---- prologue: producer runs 2 ahead
    if (w == 0) {
        ldx(0); produce(0);
        ldx(1); produce(1);
        ldx(2);
    }
    uint4 cA0, cA1, cB0, cB1;
    cload(0, cA0, cA1);

#pragma unroll 1
    for (int t = 0; t < T_STEPS; t += 2) {
        // ---- step t (even) -> Cbuf[0]
        cload(t + 1, cB0, cB1);
        if (w == 0) { produce(t + 2); ldx(t + 3); }
        consume(t, cA0, cA1, Cbuf[0]);
        LDS_BARRIER();
        rtail(Cbuf[0]);
        // ---- step t+1 (odd) -> Cbuf[1]
        cload(t + 2, cA0, cA1);                 // t+2 slot exists (padded buffer)
        if (w == 0) { produce(t + 3); ldx(t + 4); }
        consume(t + 1, cB0, cB1, Cbuf[1]);
        LDS_BARRIER();
        rtail(Cbuf[1]);
    }
}

// ---- action bit-GEMM + beta-weighted scan over t (R3..R8-proven) ----
__global__ __launch_bounds__(256) void k_act(
    const unsigned short* __restrict__ spkbits,
    const float* __restrict__ Wa, const float* __restrict__ ba,
    const float* __restrict__ beta_act_p, float* __restrict__ out)
{
    __shared__ f32x4 waT[512];
    __shared__ f32x4 sc[256];
    int tid = threadIdx.x;   // = timestep
    int b   = blockIdx.x;

    for (int j = tid; j < 512; j += 256) {
        f32x4 v = { Wa[j], Wa[512 + j], Wa[1024 + j], Wa[1536 + j] };
        waT[j] = v;
    }
    float bact = fminf(fmaxf(beta_act_p[0], 0.0f), 1.0f);
    f32x4 acc = { ba[0], ba[1], ba[2], ba[3] };
    __syncthreads();

    const unsigned short* sp = spkbits + ((size_t)tid * BATCH + b) * 32;
    unsigned int wbuf[16];
#pragma unroll
    for (int r = 0; r < 4; ++r) {
        uint4 v = *(const uint4*)(sp + r * 8);
        wbuf[r*4+0] = v.x; wbuf[r*4+1] = v.y; wbuf[r*4+2] = v.z; wbuf[r*4+3] = v.w;
    }
    for (int s = 0; s < 32; ++s) {
        unsigned int wd = (wbuf[s >> 1] >> ((s & 1) * 16)) & 0xFFFFu;
#pragma unroll
        for (int i = 0; i < 16; ++i) {
            float sel = ((wd >> i) & 1u) ? 1.0f : 0.0f;
            f32x4 wv = waT[s * 16 + i];
            acc[0] = fmaf(sel, wv[0], acc[0]);
            acc[1] = fmaf(sel, wv[1], acc[1]);
            acc[2] = fmaf(sel, wv[2], acc[2]);
            acc[3] = fmaf(sel, wv[3], acc[3]);
        }
    }
    sc[tid] = acc;
    __syncthreads();
    float bd = bact;
    for (int d = 1; d < 256; d <<= 1) {
        f32x4 cv = sc[tid];
        f32x4 pv = { 0.f, 0.f, 0.f, 0.f };
        if (tid >= d) pv = sc[tid - d];
        __syncthreads();
        cv[0] = fmaf(bd, pv[0], cv[0]);
        cv[1] = fmaf(bd, pv[1], cv[1]);
        cv[2] = fmaf(bd, pv[2], cv[2]);
        cv[3] = fmaf(bd, pv[3], cv[3]);
        sc[tid] = cv;
        __syncthreads();
        bd *= bd;
    }
    f32x4 res = sc[tid];
    *(f32x4*)(out + (size_t)tid * 512 + b * 4) = res;
}

extern "C" void kernel_launch(void* const* d_in, const int* in_sizes, int n_in,
                              void* d_out, int out_size, void* d_ws, size_t ws_size,
                              hipStream_t stream)
{
    const float* batch    = (const float*)d_in[0];
    const float* W1       = (const float*)d_in[1];
    const float* b1       = (const float*)d_in[2];
    const float* beta1    = (const float*)d_in[3];
    const float* thr1     = (const float*)d_in[4];
    const float* W2       = (const float*)d_in[5];
    const float* b2       = (const float*)d_in[6];
    const float* beta2    = (const float*)d_in[7];
    const float* thr2     = (const float*)d_in[8];
    const float* Wa       = (const float*)d_in[9];
    const float* ba       = (const float*)d_in[10];
    const float* beta_act = (const float*)d_in[11];
    const float* inp_min  = (const float*)d_in[12];
    const float* inp_max  = (const float*)d_in[13];
    float* out            = (float*)d_out;

    char* ws = (char*)d_ws;
    unsigned short* W2hi    = (unsigned short*)ws;                          // 512 KiB
    unsigned short* W2lo    = (unsigned short*)(ws + (512u << 10));         // 512 KiB
    unsigned short* W1rows  = (unsigned short*)(ws + (1u << 20));           // 64 KiB
    float*          b1s     = (float*)(ws + (1u << 20) + (64u << 10));      // 2 KiB
    unsigned short* Xf      = (unsigned short*)(ws + (2u << 20));           // 6 MiB
    unsigned short* spkbits = (unsigned short*)(ws + (8u << 20));           // 2 MiB
    unsigned*       spkglob = (unsigned*)(ws + (10u << 20));                // ~4.03 MiB (258 slots)

    hipLaunchKernelGGL(k_prep, dim3(1028), dim3(256), 0, stream,
                       W2, W1, b1, thr1, inp_min, inp_max, batch,
                       W2hi, W2lo, W1rows, b1s, Xf, spkglob);
    hipLaunchKernelGGL(k_main, dim3(256), dim3(1024), 0, stream,
                       Xf, W2hi, W2lo, W1rows, b1s, beta1, b2, beta2, thr2, spkglob, spkbits);
    hipLaunchKernelGGL(k_act, dim3(128), dim3(256), 0, stream, spkbits, Wa, ba, beta_act, out);
}

// Round 10
// 350.560 us; speedup vs baseline: 1.4886x; 1.4886x over previous
//
#include <hip/hip_runtime.h>
#include <stdint.h>

typedef __attribute__((ext_vector_type(8))) short short8;
typedef __attribute__((ext_vector_type(4))) float f32x4;

#define T_STEPS 256
#define BATCH   128

// LDS-visibility barrier that does NOT drain vmcnt (global loads stay in flight)
#define LDS_BARRIER() asm volatile("s_waitcnt lgkmcnt(0)\n\ts_barrier" ::: "memory")

static __device__ inline unsigned short f2bf(float f) {   // RNE fp32->bf16
    unsigned int u = __float_as_uint(f);
    unsigned int r = u + 0x7FFFu + ((u >> 16) & 1u);
    return (unsigned short)(r >> 16);
}
static __device__ inline unsigned pack_hi16(unsigned a, unsigned b) {
    return (a >> 16) | (b & 0xFFFF0000u);
}

// ---- k_prep: 0..255 W2 hi/lo split; 256..257 W1 3-split rows (scaled 1/thr1); 258..769 X B-frags
__global__ __launch_bounds__(256) void k_prep(
    const float* __restrict__ W2, const float* __restrict__ W1,
    const float* __restrict__ b1, const float* __restrict__ thr1,
    const float* __restrict__ imin_p, const float* __restrict__ imax_p,
    const float* __restrict__ batch,
    unsigned short* __restrict__ W2hi, unsigned short* __restrict__ W2lo,
    unsigned short* __restrict__ W1rows, float* __restrict__ b1s,
    unsigned short* __restrict__ Xf)
{
    int blk = blockIdx.x, tid = threadIdx.x;
    if (blk < 256) {
        int gid = blk * 256 + tid;
        f32x4 wv = *(const f32x4*)(W2 + (size_t)gid * 4);
        unsigned short hi[4], lo[4];
#pragma unroll
        for (int e = 0; e < 4; ++e) {
            float wf = wv[e];
            unsigned short h = f2bf(wf);
            float hf = __uint_as_float(((unsigned int)h) << 16);
            hi[e] = h;
            lo[e] = f2bf(wf - hf);
        }
        uint2 ph, pl;
        ph.x = (unsigned)hi[0] | ((unsigned)hi[1] << 16);
        ph.y = (unsigned)hi[2] | ((unsigned)hi[3] << 16);
        pl.x = (unsigned)lo[0] | ((unsigned)lo[1] << 16);
        pl.y = (unsigned)lo[2] | ((unsigned)lo[3] << 16);
        *(uint2*)(W2hi + (size_t)gid * 4) = ph;
        *(uint2*)(W2lo + (size_t)gid * 4) = pl;
    } else if (blk < 258) {
        int h = (blk - 256) * 256 + tid;
        float wsc = 1.0f / thr1[h];
        unsigned short row[64];
#pragma unroll
        for (int k = 0; k < 16; ++k) {
            float wv = W1[h * 16 + k] * wsc;
            unsigned a = __float_as_uint(wv) & 0xFFFF0000u;
            float r1 = wv - __uint_as_float(a);
            unsigned m = __float_as_uint(r1) & 0xFFFF0000u;
            float r2 = r1 - __uint_as_float(m);
            unsigned l = __float_as_uint(r2) & 0xFFFF0000u;
            row[k]      = (unsigned short)(a >> 16);
            row[16 + k] = (unsigned short)(m >> 16);
            row[32 + k] = (unsigned short)(l >> 16);
            row[48 + k] = 0;
        }
        b1s[h] = b1[h] * wsc;
        uint4* dst = (uint4*)(W1rows + (size_t)h * 64);
#pragma unroll
        for (int i = 0; i < 8; ++i) dst[i] = ((uint4*)row)[i];
    } else {
        int gid   = (blk - 258) * 256 + tid;
        int lane  = gid & 63;
        int btile = (gid >> 6) & 7;
        int t     = gid >> 9;
        int q     = lane >> 4, m15 = lane & 15;
        int b     = btile * 16 + m15;
        float imin = imin_p[0];
        float isc  = 1.0f / (imax_p[0] - imin);
        const float* xp = batch + ((size_t)b * T_STEPS + t) * 16 + (q & 1) * 8;
        unsigned uh[8], um[8], ul[8];
#pragma unroll
        for (int j = 0; j < 8; ++j) {
            float xv = (xp[j] - imin) * isc;
            unsigned a = __float_as_uint(xv) & 0xFFFF0000u;
            float r1 = xv - __uint_as_float(a);
            unsigned m = __float_as_uint(r1) & 0xFFFF0000u;
            float r2 = r1 - __uint_as_float(m);
            unsigned l = __float_as_uint(r2) & 0xFFFF0000u;
            uh[j] = a; um[j] = m; ul[j] = l;
        }
        uint4 B1, B2, XL;
        B1.x = pack_hi16(uh[0], uh[1]); B1.y = pack_hi16(uh[2], uh[3]);
        B1.z = pack_hi16(uh[4], uh[5]); B1.w = pack_hi16(uh[6], uh[7]);
        B2.x = pack_hi16(um[0], um[1]); B2.y = pack_hi16(um[2], um[3]);
        B2.z = pack_hi16(um[4], um[5]); B2.w = pack_hi16(um[6], um[7]);
        XL.x = pack_hi16(ul[0], ul[1]); XL.y = pack_hi16(ul[2], ul[3]);
        XL.z = pack_hi16(ul[4], ul[5]); XL.w = pack_hi16(ul[6], ul[7]);
        uint4 B3 = (q < 2) ? XL : B1;   // [xl|xh]
        unsigned short* dst = Xf + (((size_t)t * 8 + btile) * 3) * 512 + lane * 8;
        *(uint4*)(dst +    0) = B1;
        *(uint4*)(dst +  512) = B2;
        *(uint4*)(dst + 1024) = B3;
    }
}

// ---- k_spk1: layer-1 spike trains (feedforward — no layer-2 feedback).
// 32 blocks (8 btile x 4 hslice of 128 h) x 512 thr (8 waves of 16 h each).
// Per wave-step: GEMM1 (3 MFMA, 3-split), LIF1 (4 states/lane), ballot -> bit dword per h.
__global__ __launch_bounds__(512, 2) void k_spk1(
    const unsigned short* __restrict__ Xf, const unsigned short* __restrict__ W1rows,
    const float* __restrict__ b1s, const float* __restrict__ beta1,
    unsigned* __restrict__ spkglob)
{
    int tid  = threadIdx.x;
    int lane = tid & 63;
    int w    = tid >> 6;                  // 0..7
    int q    = lane >> 4, m15 = lane & 15;
    int btile = blockIdx.x & 7;
    int hs    = blockIdx.x >> 3;          // 0..3
    int hbase = hs * 128 + w * 16;

    const unsigned short* rp = W1rows + (size_t)(hbase + m15) * 64;
    short8 A1p = *(const short8*)(rp + q * 8);
    short8 A2p = *(const short8*)(rp + q * 8 + (q >> 1) * 16);
    int h0p = hbase + q * 4;
    f32x4 b14p = *(const f32x4*)(b1s + h0p);
    f32x4 bet1p;
    {
        f32x4 bb = *(const f32x4*)(beta1 + h0p);
#pragma unroll
        for (int r = 0; r < 4; ++r) bet1p[r] = fminf(fmaxf(bb[r], 0.0f), 1.0f);
    }
    float m1p[4] = { 0.f, 0.f, 0.f, 0.f }, sp1p[4] = { 0.f, 0.f, 0.f, 0.f };

    const unsigned short* xbase = Xf + ((size_t)btile * 3) * 512 + lane * 8;
    unsigned* pstore = spkglob + (size_t)btile * 512 + hbase + (lane & 15);

    uint4 xc[3], xn[3];
#pragma unroll
    for (int f = 0; f < 3; ++f) xc[f] = *(const uint4*)(xbase + f * 512);

#pragma unroll 1
    for (int t = 0; t < T_STEPS; ++t) {
        // prefetch x(t+1)
        int tn = (t + 1 < T_STEPS) ? t + 1 : t;
        const unsigned short* xp = xbase + (size_t)tn * 12288;
#pragma unroll
        for (int f = 0; f < 3; ++f) xn[f] = *(const uint4*)(xp + f * 512);

        union { uint4 u; short8 s; } B0, B1, B2;
        B0.u = xc[0]; B1.u = xc[1]; B2.u = xc[2];
        f32x4 D = b14p;
        D = __builtin_amdgcn_mfma_f32_16x16x32_bf16(A1p, B0.s, D, 0, 0, 0);
        D = __builtin_amdgcn_mfma_f32_16x16x32_bf16(A1p, B1.s, D, 0, 0, 0);
        D = __builtin_amdgcn_mfma_f32_16x16x32_bf16(A2p, B2.s, D, 0, 0, 0);
        unsigned long long mk[4];
#pragma unroll
        for (int r = 0; r < 4; ++r) {
            float mv = fmaf(bet1p[r], m1p[r], D[r]);
            mv -= sp1p[r];
            bool sp = mv > 1.0f;
            m1p[r] = mv;
            sp1p[r] = sp ? 1.0f : 0.0f;
            mk[r] = __ballot(sp);
        }
        if (lane < 16) {
            int rs = lane & 3, qs = lane >> 2;
            unsigned long long mv_ = mk[0];
            mv_ = (rs == 1) ? mk[1] : mv_;
            mv_ = (rs == 2) ? mk[2] : mv_;
            mv_ = (rs == 3) ? mk[3] : mv_;
            unsigned dw  = (qs & 2) ? (unsigned)(mv_ >> 32) : (unsigned)mv_;
            unsigned v16 = (qs & 1) ? (dw >> 16) : (dw & 0xFFFFu);
            pstore[(size_t)t * 4096] = v16;
        }
#pragma unroll
        for (int f = 0; f < 3; ++f) xc[f] = xn[f];
    }
}

// ---- k_main2: GEMM2 + LIF2 scan. 256 blocks x 16 waves; spikes from global (read-only).
// 2 steps per barrier-pair; spike loads prefetched 2 steps ahead.
__global__ __launch_bounds__(1024, 4) void k_main2(
    const unsigned short* __restrict__ W2hi, const unsigned short* __restrict__ W2lo,
    const float* __restrict__ pb2, const float* __restrict__ beta2,
    const float* __restrict__ thr2,
    const unsigned* __restrict__ spkglob, unsigned short* __restrict__ spkbits)
{
    __shared__ float Cbuf[2][4096];       // [buf][r 4][wp 16][lane^swz 64]

    int tid  = threadIdx.x;
    int lane = tid & 63;
    int w    = tid >> 6;
    int q    = lane >> 4, m15 = lane & 15;
    int btile = blockIdx.x & 7;
    int slice = blockIdx.x >> 3;
    int rr = w & 3, qi = w >> 2;

    int jg = slice * 16 + m15;
    short8 bhi = *(const short8*)(W2hi + (size_t)jg * 512 + w * 32 + q * 8);
    short8 blo = *(const short8*)(W2lo + (size_t)jg * 512 + w * 32 + q * 8);

    float beta2r = fminf(fmaxf(beta2[jg], 0.0f), 1.0f);
    float thr2r  = thr2[jg];
    float nthr2  = -thr2r;
    float b2r    = pb2[jg];
    float m2 = 0.0f, spk2f = 0.0f;

    int sidx = w * 64 + (lane ^ (qi * 16));
    int ridx = rr * 1024 + q * 256 + ((qi ^ q) * 16 + m15);
    unsigned short* spkp = spkbits + ((size_t)btile * 16 + (qi * 4 + rr)) * 32 + slice;
    const unsigned* cbase = spkglob + (size_t)btile * 512 + w * 32 + q * 8;

    auto cload = [&](int t, uint4& a, uint4& b) __attribute__((always_inline)) {
        int tn = (t < T_STEPS) ? t : T_STEPS - 1;
        const unsigned* p = cbase + (size_t)tn * 4096;
        a = *(const uint4*)(p);
        b = *(const uint4*)(p + 4);
    };
    auto scat = [&](uint4 a, uint4 b, float* cb) __attribute__((always_inline)) {
        union { unsigned u[4]; short8 s; } af;
        af.u[0] = (((a.x >> m15) & 1) ? 0x3F80u : 0u) | (((a.y >> m15) & 1) ? 0x3F800000u : 0u);
        af.u[1] = (((a.z >> m15) & 1) ? 0x3F80u : 0u) | (((a.w >> m15) & 1) ? 0x3F800000u : 0u);
        af.u[2] = (((b.x >> m15) & 1) ? 0x3F80u : 0u) | (((b.y >> m15) & 1) ? 0x3F800000u : 0u);
        af.u[3] = (((b.z >> m15) & 1) ? 0x3F80u : 0u) | (((b.w >> m15) & 1) ? 0x3F800000u : 0u);
        f32x4 C2 = { 0.f, 0.f, 0.f, 0.f };
        C2 = __builtin_amdgcn_mfma_f32_16x16x32_bf16(af.s, bhi, C2, 0, 0, 0);
        C2 = __builtin_amdgcn_mfma_f32_16x16x32_bf16(af.s, blo, C2, 0, 0, 0);
        cb[sidx]        = C2[0];
        cb[sidx + 1024] = C2[1];
        cb[sidx + 2048] = C2[2];
        cb[sidx + 3072] = C2[3];
    };
    auto rtail = [&](const float* cb) __attribute__((always_inline)) {
        float s0 = cb[ridx], s1 = cb[ridx + 64], s2 = cb[ridx + 128], s3 = cb[ridx + 192];
        float s = (s0 + s1) + (s2 + s3);
        s += __shfl_xor(s, 16, 64);
        s += __shfl_xor(s, 32, 64);
        m2 = fmaf(beta2r, m2, b2r + s);
        m2 = fmaf(spk2f, nthr2, m2);
        bool sp2 = m2 > thr2r;
        spk2f = sp2 ? 1.0f : 0.0f;
        unsigned long long mask = __ballot(sp2);
        if (lane == 0) *spkp = (unsigned short)(mask & 0xFFFFu);
        spkp += BATCH * 32;
    };

    uint4 a0, c0, a1, c1, a2, c2, a3, c3;
    cload(0, a0, c0);
    cload(1, a1, c1);

#pragma unroll 1
    for (int t = 0; t < T_STEPS; t += 2) {
        cload(t + 2, a2, c2);            // in flight across both barriers
        cload(t + 3, a3, c3);
        scat(a0, c0, Cbuf[0]);
        scat(a1, c1, Cbuf[1]);
        LDS_BARRIER();
        rtail(Cbuf[0]);
        rtail(Cbuf[1]);
        LDS_BARRIER();
        a0 = a2; c0 = c2; a1 = a3; c1 = c3;
    }
}

// ---- action bit-GEMM + beta-weighted scan over t (R3..R8-proven) ----
__global__ __launch_bounds__(256) void k_act(
    const unsigned short* __restrict__ spkbits,
    const float* __restrict__ Wa, const float* __restrict__ ba,
    const float* __restrict__ beta_act_p, float* __restrict__ out)
{
    __shared__ f32x4 waT[512];
    __shared__ f32x4 sc[256];
    int tid = threadIdx.x;   // = timestep
    int b   = blockIdx.x;

    for (int j = tid; j < 512; j += 256) {
        f32x4 v = { Wa[j], Wa[512 + j], Wa[1024 + j], Wa[1536 + j] };
        waT[j] = v;
    }
    float bact = fminf(fmaxf(beta_act_p[0], 0.0f), 1.0f);
    f32x4 acc = { ba[0], ba[1], ba[2], ba[3] };
    __syncthreads();

    const unsigned short* sp = spkbits + ((size_t)tid * BATCH + b) * 32;
    unsigned int wbuf[16];
#pragma unroll
    for (int r = 0; r < 4; ++r) {
        uint4 v = *(const uint4*)(sp + r * 8);
        wbuf[r*4+0] = v.x; wbuf[r*4+1] = v.y; wbuf[r*4+2] = v.z; wbuf[r*4+3] = v.w;
    }
    for (int s = 0; s < 32; ++s) {
        unsigned int wd = (wbuf[s >> 1] >> ((s & 1) * 16)) & 0xFFFFu;
#pragma unroll
        for (int i = 0; i < 16; ++i) {
            float sel = ((wd >> i) & 1u) ? 1.0f : 0.0f;
            f32x4 wv = waT[s * 16 + i];
            acc[0] = fmaf(sel, wv[0], acc[0]);
            acc[1] = fmaf(sel, wv[1], acc[1]);
            acc[2] = fmaf(sel, wv[2], acc[2]);
            acc[3] = fmaf(sel, wv[3], acc[3]);
        }
    }
    sc[tid] = acc;
    __syncthreads();
    float bd = bact;
    for (int d = 1; d < 256; d <<= 1) {
        f32x4 cv = sc[tid];
        f32x4 pv = { 0.f, 0.f, 0.f, 0.f };
        if (tid >= d) pv = sc[tid - d];
        __syncthreads();
        cv[0] = fmaf(bd, pv[0], cv[0]);
        cv[1] = fmaf(bd, pv[1], cv[1]);
        cv[2] = fmaf(bd, pv[2], cv[2]);
        cv[3] = fmaf(bd, pv[3], cv[3]);
        sc[tid] = cv;
        __syncthreads();
        bd *= bd;
    }
    f32x4 res = sc[tid];
    *(f32x4*)(out + (size_t)tid * 512 + b * 4) = res;
}

extern "C" void kernel_launch(void* const* d_in, const int* in_sizes, int n_in,
                              void* d_out, int out_size, void* d_ws, size_t ws_size,
                              hipStream_t stream)
{
    const float* batch    = (const float*)d_in[0];
    const float* W1       = (const float*)d_in[1];
    const float* b1       = (const float*)d_in[2];
    const float* beta1    = (const float*)d_in[3];
    const float* thr1     = (const float*)d_in[4];
    const float* W2       = (const float*)d_in[5];
    const float* b2       = (const float*)d_in[6];
    const float* beta2    = (const float*)d_in[7];
    const float* thr2     = (const float*)d_in[8];
    const float* Wa       = (const float*)d_in[9];
    const float* ba       = (const float*)d_in[10];
    const float* beta_act = (const float*)d_in[11];
    const float* inp_min  = (const float*)d_in[12];
    const float* inp_max  = (const float*)d_in[13];
    float* out            = (float*)d_out;

    char* ws = (char*)d_ws;
    unsigned short* W2hi    = (unsigned short*)ws;                          // 512 KiB
    unsigned short* W2lo    = (unsigned short*)(ws + (512u << 10));         // 512 KiB
    unsigned short* W1rows  = (unsigned short*)(ws + (1u << 20));           // 64 KiB
    float*          b1s     = (float*)(ws + (1u << 20) + (64u << 10));      // 2 KiB
    unsigned short* Xf      = (unsigned short*)(ws + (2u << 20));           // 6 MiB
    unsigned short* spkbits = (unsigned short*)(ws + (8u << 20));           // 2 MiB
    unsigned*       spkglob = (unsigned*)(ws + (10u << 20));                // 4 MiB

    hipLaunchKernelGGL(k_prep, dim3(770), dim3(256), 0, stream,
                       W2, W1, b1, thr1, inp_min, inp_max, batch,
                       W2hi, W2lo, W1rows, b1s, Xf);
    hipLaunchKernelGGL(k_spk1, dim3(32), dim3(512), 0, stream,
                       Xf, W1rows, b1s, beta1, spkglob);
    hipLaunchKernelGGL(k_main2, dim3(256), dim3(1024), 0, stream,
                       W2hi, W2lo, b2, beta2, thr2, spkglob, spkbits);
    hipLaunchKernelGGL(k_act, dim3(128), dim3(256), 0, stream, spkbits, Wa, ba, beta_act, out);
}